// Round 4
// baseline (24969.572 us; speedup 1.0000x reference)
//
#include <hip/hip_runtime.h>
#include <hip/hip_bf16.h>
#include <math.h>

#define BB 64      // batch
#define TT 512     // encoder time
#define NS 128     // decode steps
#define SD 512     // lstm hidden
#define ATT 128
#define NC 64      // num classes
#define KA 1152    // augmented K: 512 in + 512 rec + 64 onehot + 1 bias + 63 pad
#define NBLK 256   // persistent grid (<= 256 CUs; capacity >= 2 blocks/CU -> all resident)

typedef __attribute__((ext_vector_type(8))) short bf8;   // 8 bf16 (4 VGPRs)
typedef __attribute__((ext_vector_type(4))) float f4;

__device__ __forceinline__ float sigm(float x) { return 1.0f / (1.0f + expf(-x)); }
__device__ __forceinline__ float b2f(short s) {
    union { unsigned u; float f; } c; c.u = ((unsigned)(unsigned short)s) << 16; return c.f;
}
#define MFMA16(a, b, c) __builtin_amdgcn_mfma_f32_16x16x32_bf16((a), (b), (c), 0, 0, 0)

// ---------------- epoch grid barrier (device-scope, non-cooperative) ----------------
__device__ __forceinline__ void gbar(unsigned* bar, unsigned target) {
    __syncthreads();                       // all waves' work done
    if (threadIdx.x == 0) {
        __threadfence();                   // release: make this block's stores visible
        atomicAdd(bar, 1u);
        while (__hip_atomic_load(bar, __ATOMIC_ACQUIRE, __HIP_MEMORY_SCOPE_AGENT) < target)
            __builtin_amdgcn_s_sleep(1);
        __threadfence();                   // acquire: invalidate stale cached lines
    }
    __syncthreads();
}

// ---------------- fp32 -> bf16 convert (vec4) ----------------
__global__ void f2b_kernel(const float* __restrict__ src, __hip_bfloat16* __restrict__ dst, int n)
{
    int i = (blockIdx.x * blockDim.x + threadIdx.x) * 4;
    if (i < n) {
        float4 v = *(const float4*)(src + i);
        dst[i]     = __hip_bfloat16(v.x);
        dst[i + 1] = __hip_bfloat16(v.y);
        dst[i + 2] = __hip_bfloat16(v.z);
        dst[i + 3] = __hip_bfloat16(v.w);
    }
}

// ---------------- small weights bf16 convert (all 65536 elems each) ----------------
__global__ void prep_small_kernel(const float* __restrict__ Wphi, const float* __restrict__ Wpsi,
                                  const float* __restrict__ Wcd,
                                  __hip_bfloat16* __restrict__ Wphib, __hip_bfloat16* __restrict__ Wpsib,
                                  __hip_bfloat16* __restrict__ Wcdb)
{
    int i = blockIdx.x * 256 + threadIdx.x;
    Wphib[i] = __hip_bfloat16(Wphi[i]);
    Wpsib[i] = __hip_bfloat16(Wpsi[i]);
    Wcdb[i]  = __hip_bfloat16(Wcd[i]);
}

// ---------------- build augmented LSTM weights, gate-interleaved np=4d+q ----------------
__global__ void prep_w_kernel(const float* __restrict__ Wih0, const float* __restrict__ Whh0,
                              const float* __restrict__ bih0, const float* __restrict__ bhh0,
                              const float* __restrict__ Wih1, const float* __restrict__ Whh1,
                              const float* __restrict__ bih1, const float* __restrict__ bhh1,
                              __hip_bfloat16* __restrict__ W1, __hip_bfloat16* __restrict__ W2)
{
    int idx = blockIdx.x * 256 + threadIdx.x;
    const int half = 2048 * KA;
    if (idx >= 2 * half) return;
    int which = idx >= half;
    int id = idx - which * half;
    int np = id / KA, kk = id - np * KA;
    int q = np & 3, d = np >> 2, j = q * 512 + d;
    float v = 0.f;
    if (!which) {
        if (kk < 512)        v = Wih0[j * 576 + 64 + kk];
        else if (kk < 1024)  v = Whh0[j * 512 + kk - 512];
        else if (kk < 1088)  v = Wih0[j * 576 + kk - 1024];
        else if (kk == 1088) v = bih0[j] + bhh0[j];
        W1[id] = __hip_bfloat16(v);
    } else {
        if (kk < 512)        v = Wih1[j * 512 + kk];
        else if (kk < 1024)  v = Whh1[j * 512 + kk - 512];
        else if (kk == 1088) v = bih1[j] + bhh1[j];
        W2[id] = __hip_bfloat16(v);
    }
}

// ---------------- init: X buffers, c states, barrier counter ----------------
__global__ void init_kernel(const float* __restrict__ h, const int* __restrict__ x,
                            __hip_bfloat16* __restrict__ X1a, __hip_bfloat16* __restrict__ X1b,
                            __hip_bfloat16* __restrict__ X2a, __hip_bfloat16* __restrict__ X2b,
                            float* __restrict__ c1, float* __restrict__ c2,
                            unsigned* __restrict__ bar)
{
    int idx = blockIdx.x * blockDim.x + threadIdx.x;   // 64*1152
    if (blockIdx.x == 0 && threadIdx.x == 0) *bar = 0u;
    if (idx >= 64 * KA) return;
    int b = idx / KA, col = idx - b * KA;
    __hip_bfloat16 zero(0.0f), one(1.0f);
    __hip_bfloat16 v1a = zero, vo = zero;
    if (col < 512)        v1a = __hip_bfloat16(h[(size_t)b * TT * SD + col]);  // ctx0 = h[:,0,:]
    else if (col >= 1024 && col < 1088) v1a = (x[b * NS] == col - 1024) ? one : zero;
    if (col == 1088) { v1a = one; vo = one; }
    X1a[idx] = v1a; X1b[idx] = vo; X2a[idx] = vo; X2b[idx] = vo;
    if (idx < 512 * 64) { c1[idx] = 0.f; c2[idx] = 0.f; }
}

// ---------------- psi GEMM: psibf[b*512+t][128] = hbf @ Wpsi^T + bpsi ----------------
__global__ __launch_bounds__(256) void psi_gemm_kernel(
    const __hip_bfloat16* __restrict__ A,   // hbf [32768][512]
    const __hip_bfloat16* __restrict__ Bw,  // Wpsibf [128][512]
    const float* __restrict__ bias,
    __hip_bfloat16* __restrict__ C)         // [32768][128]
{
    int lane = threadIdx.x & 63, wave = threadIdx.x >> 6;
    int m0 = (blockIdx.x * 4 + wave) * 16;
    int mr = lane & 15, quad = lane >> 4;
    const bf8* Ar = (const bf8*)(A + (size_t)(m0 + mr) * 512 + quad * 8);
    f4 acc[8] = {};
    for (int k0 = 0; k0 < 512; k0 += 32) {
        int ko = k0 >> 3;
        bf8 a = Ar[ko];
#pragma unroll
        for (int nf = 0; nf < 8; ++nf) {
            const bf8* Br = (const bf8*)(Bw + (size_t)(nf * 16 + mr) * 512 + quad * 8);
            acc[nf] = MFMA16(a, Br[ko], acc[nf]);
        }
    }
#pragma unroll
    for (int nf = 0; nf < 8; ++nf) {
        int n = nf * 16 + mr;
        float bs = bias[n];
#pragma unroll
        for (int r = 0; r < 4; ++r) {
            int m = m0 + quad * 4 + r;
            C[(size_t)m * 128 + n] = __hip_bfloat16(acc[nf][r] + bs);
        }
    }
}

// ---------------- LSTM phase (device fn): K-split 4 waves, LDS reduce, cell ----------------
__device__ __forceinline__ void lstm_phase(
    const __hip_bfloat16* __restrict__ X,    // [64][1152]
    const __hip_bfloat16* __restrict__ W,    // [2048][1152] gate-interleaved
    float* __restrict__ c,
    __hip_bfloat16* dst1, int rs1,
    __hip_bfloat16* dst2, int rs2,
    float* smem, int bid, int tid)
{
    int lane = tid & 63, w = tid >> 6;
    int mr = lane & 15, quad = lane >> 4;
    int m0 = bid * 16;
    int kbase = w * 288 + quad * 8;          // this wave's K-slice
    const bf8* Ar = (const bf8*)(W + (size_t)(m0 + mr) * KA + kbase);
    const bf8* B0 = (const bf8*)(X + (size_t)(mr)      * KA + kbase);
    const bf8* B1 = (const bf8*)(X + (size_t)(16 + mr) * KA + kbase);
    const bf8* B2 = (const bf8*)(X + (size_t)(32 + mr) * KA + kbase);
    const bf8* B3 = (const bf8*)(X + (size_t)(48 + mr) * KA + kbase);
    f4 a0 = {0,0,0,0}, a1 = {0,0,0,0}, a2 = {0,0,0,0}, a3 = {0,0,0,0};
#pragma unroll
    for (int i = 0; i < 9; ++i) {
        int ko = i * 4;
        bf8 av = Ar[ko];
        bf8 b0 = B0[ko], b1 = B1[ko], b2 = B2[ko], b3 = B3[ko];
        a0 = MFMA16(av, b0, a0);
        a1 = MFMA16(av, b1, a1);
        a2 = MFMA16(av, b2, a2);
        a3 = MFMA16(av, b3, a3);
    }
    f4 accs[4] = {a0, a1, a2, a3};
#pragma unroll
    for (int nf = 0; nf < 4; ++nf)
#pragma unroll
        for (int r = 0; r < 4; ++r)
            smem[w * 1024 + (quad * 4 + r) * 64 + nf * 16 + mr] = accs[nf][r];
    __syncthreads();
    // epilogue: thread (d_loc, b)
    int d_loc = tid >> 6, b = tid & 63;
    float g[4];
#pragma unroll
    for (int q = 0; q < 4; ++q) {
        int m = d_loc * 4 + q;
        g[q] = smem[m * 64 + b] + smem[1024 + m * 64 + b]
             + smem[2048 + m * 64 + b] + smem[3072 + m * 64 + b];
    }
    int d = bid * 4 + d_loc;
    int ci = d * 64 + b;
    float cn = sigm(g[1]) * c[ci] + sigm(g[0]) * tanhf(g[2]);
    float hn = sigm(g[3]) * tanhf(cn);
    c[ci] = cn;
    __hip_bfloat16 hb(hn);
    dst1[(size_t)b * rs1 + d] = hb;
    dst2[(size_t)b * rs2 + d] = hb;
}

// ---------------- attention phase (device fn) ----------------
__device__ __forceinline__ void attn_phase(
    const __hip_bfloat16* __restrict__ X2n,   // h2 at cols 512:1024
    const __hip_bfloat16* __restrict__ Wphib, const float* __restrict__ bphi,
    const __hip_bfloat16* __restrict__ psib,
    const __hip_bfloat16* __restrict__ hbf,
    __hip_bfloat16* X1n, __hip_bfloat16* scb,
    const int* __restrict__ xtok, int t,
    float* smem, int bid, int tid)
{
    int b = bid >> 2, dch = bid & 3;
    float* h2s  = smem;
    float* phis = smem + 512;
    float* es   = smem + 1024;
    float* red  = smem + 1536;

    h2s[tid]       = b2f(((const short*)X2n)[b * KA + 512 + tid]);
    h2s[256 + tid] = b2f(((const short*)X2n)[b * KA + 768 + tid]);
    __syncthreads();

    // phi[a] = h2 . Wphi[a] + bphi[a];  4 lanes/row
    {
        int al = tid & 3;
#pragma unroll
        for (int pass = 0; pass < 2; ++pass) {
            int a = pass * 64 + (tid >> 2);
            const bf8* wr = (const bf8*)(Wphib + (size_t)a * 512 + al * 8);
            float acc = 0.f;
#pragma unroll
            for (int i = 0; i < 16; ++i) {
                bf8 wv = wr[i * 4];
                const float* hp = h2s + i * 32 + al * 8;
#pragma unroll
                for (int j = 0; j < 8; ++j) acc += hp[j] * b2f(wv[j]);
            }
            acc += __shfl_xor(acc, 1);
            acc += __shfl_xor(acc, 2);
            if (al == 0) phis[a] = acc + bphi[a];
        }
    }
    __syncthreads();

    // e[t'] = phi . psi[b][t'];  4 lanes/row
    {
        int al = tid & 3;
#pragma unroll
        for (int pass = 0; pass < 8; ++pass) {
            int tt = pass * 64 + (tid >> 2);
            const bf8* pr = (const bf8*)(psib + (size_t)(b * TT + tt) * 128 + al * 8);
            float acc = 0.f;
#pragma unroll
            for (int i = 0; i < 4; ++i) {
                bf8 pv = pr[i * 4];
                const float* ph = phis + i * 32 + al * 8;
#pragma unroll
                for (int j = 0; j < 8; ++j) acc += ph[j] * b2f(pv[j]);
            }
            acc += __shfl_xor(acc, 1);
            acc += __shfl_xor(acc, 2);
            if (al == 0) es[tt] = acc;
        }
    }
    __syncthreads();

    // softmax (unnormalized; fold 1/sum into ctx)
    red[tid] = fmaxf(es[tid], es[tid + 256]);
    __syncthreads();
    for (int st = 128; st > 0; st >>= 1) {
        if (tid < st) red[tid] = fmaxf(red[tid], red[tid + st]);
        __syncthreads();
    }
    float mx = red[0];
    __syncthreads();
    float e0 = expf(es[tid] - mx), e1 = expf(es[tid + 256] - mx);
    es[tid] = e0; es[tid + 256] = e1;
    red[tid] = e0 + e1;
    __syncthreads();
    for (int st = 128; st > 0; st >>= 1) {
        if (tid < st) red[tid] += red[tid + st];
        __syncthreads();
    }
    float inv = 1.0f / red[0];
    __syncthreads();

    // ctx[d] = inv * sum_t es[t] * h[b][t][d], d-chunk of 128
    {
        int d = dch * 128 + (tid & 127), th = tid >> 7;
        const short* hp = (const short*)hbf + ((size_t)b * TT + th * 256) * SD + d;
        float s0 = 0.f, s1 = 0.f, s2 = 0.f, s3 = 0.f;
#pragma unroll 4
        for (int k = 0; k < 256; k += 4) {
            s0 += es[th * 256 + k]     * b2f(hp[(size_t)k * SD]);
            s1 += es[th * 256 + k + 1] * b2f(hp[(size_t)(k + 1) * SD]);
            s2 += es[th * 256 + k + 2] * b2f(hp[(size_t)(k + 2) * SD]);
            s3 += es[th * 256 + k + 3] * b2f(hp[(size_t)(k + 3) * SD]);
        }
        float acc = (s0 + s1) + (s2 + s3);
        red[tid] = acc;
        __syncthreads();
        if (th == 0) {
            float v = (acc + red[tid + 128]) * inv;
            __hip_bfloat16 vb(v);
            X1n[b * KA + d] = vb;
            scb[((size_t)b * NS + t) * 1024 + 512 + d] = vb;
        }
    }
    if (tid < 64) {
        float v = (t + 1 < NS && xtok[b * NS + t + 1] == tid) ? 1.0f : 0.0f;
        X1n[b * KA + 1024 + tid] = __hip_bfloat16(v);
    }
}

// ---------------- persistent decode kernel (plain launch, grid=256) ----------------
__global__ __launch_bounds__(256, 1) void decode_kernel(
    const __hip_bfloat16* __restrict__ W1, const __hip_bfloat16* __restrict__ W2,
    const __hip_bfloat16* __restrict__ Wphib, const float* __restrict__ bphi,
    const __hip_bfloat16* __restrict__ psib, const __hip_bfloat16* __restrict__ hbf,
    const __hip_bfloat16* __restrict__ Wcdb, const float* __restrict__ bcd,
    __hip_bfloat16* X1a, __hip_bfloat16* X1b,
    __hip_bfloat16* X2a, __hip_bfloat16* X2b,
    float* c1, float* c2,
    __hip_bfloat16* scb, const int* __restrict__ xtok,
    float* out, unsigned* bar)
{
    __shared__ float smem[4096];
    int bid = blockIdx.x, tid = threadIdx.x;
    unsigned ep = 0;

    for (int t = 0; t < NS; ++t) {
        __hip_bfloat16 *X1c, *X1n, *X2c, *X2n;
        if (t & 1) { X1c = X1b; X1n = X1a; X2c = X2b; X2n = X2a; }
        else       { X1c = X1a; X1n = X1b; X2c = X2a; X2n = X2b; }

        if (bid < 128)
            lstm_phase(X1c, W1, c1, X2c, KA, X1n + 512, KA, smem, bid, tid);
        gbar(bar, ++ep * NBLK);

        if (bid < 128)
            lstm_phase(X2c, W2, c2, X2n + 512, KA, scb + (size_t)t * 1024, NS * 1024, smem, bid, tid);
        gbar(bar, ++ep * NBLK);

        attn_phase(X2n, Wphib, bphi, psib, hbf, X1n, scb, xtok, t, smem, bid, tid);
        gbar(bar, ++ep * NBLK);
    }

    // ---- output projection: out[m][n] = scb[m,:1024]·Wcd[n,:1024] + bcd[n] ----
    int lane = tid & 63, w = tid >> 6;
    int gw = bid * 4 + w;
    if (gw < 512) {
        int mr = lane & 15, quad = lane >> 4;
        int m0 = gw * 16;
        const bf8* Ar = (const bf8*)(scb + (size_t)(m0 + mr) * 1024 + quad * 8);
        f4 acc[4] = {};
        for (int k0 = 0; k0 < 1024; k0 += 32) {
            int ko = k0 >> 3;
            bf8 a = Ar[ko];
#pragma unroll
            for (int nf = 0; nf < 4; ++nf) {
                const bf8* Br = (const bf8*)(Wcdb + (size_t)(nf * 16 + mr) * 1024 + quad * 8);
                acc[nf] = MFMA16(a, Br[ko], acc[nf]);
            }
        }
#pragma unroll
        for (int nf = 0; nf < 4; ++nf) {
            int n = nf * 16 + mr;
            float bs = bcd[n];
#pragma unroll
            for (int r = 0; r < 4; ++r)
                out[(size_t)(m0 + quad * 4 + r) * 64 + n] = acc[nf][r] + bs;
        }
    }
}

extern "C" void kernel_launch(void* const* d_in, const int* in_sizes, int n_in,
                              void* d_out, int out_size, void* d_ws, size_t ws_size,
                              hipStream_t stream)
{
    const int*   x    = (const int*)  d_in[0];
    const float* h    = (const float*)d_in[1];
    const float* Wih0 = (const float*)d_in[2];
    const float* Whh0 = (const float*)d_in[3];
    const float* bih0 = (const float*)d_in[4];
    const float* bhh0 = (const float*)d_in[5];
    const float* Wih1 = (const float*)d_in[6];
    const float* Whh1 = (const float*)d_in[7];
    const float* bih1 = (const float*)d_in[8];
    const float* bhh1 = (const float*)d_in[9];
    const float* Wphi = (const float*)d_in[10];
    const float* bphi = (const float*)d_in[11];
    const float* Wpsi = (const float*)d_in[12];
    const float* bpsi = (const float*)d_in[13];
    const float* Wcd  = (const float*)d_in[14];
    const float* bcd  = (const float*)d_in[15];
    float* out = (float*)d_out;

    char* p = (char*)d_ws;
    __hip_bfloat16* hbf   = (__hip_bfloat16*)p; p += (size_t)BB * TT * SD * 2;   // 32 MB
    __hip_bfloat16* psibf = (__hip_bfloat16*)p; p += (size_t)BB * TT * ATT * 2;  // 8 MB
    __hip_bfloat16* scbf  = (__hip_bfloat16*)p; p += (size_t)BB * NS * 1024 * 2; // 16 MB
    __hip_bfloat16* W1aug = (__hip_bfloat16*)p; p += (size_t)2048 * KA * 2;      // 4.5 MB
    __hip_bfloat16* W2aug = (__hip_bfloat16*)p; p += (size_t)2048 * KA * 2;      // 4.5 MB
    __hip_bfloat16* Wphib = (__hip_bfloat16*)p; p += (size_t)ATT * SD * 2;
    __hip_bfloat16* Wpsib = (__hip_bfloat16*)p; p += (size_t)ATT * SD * 2;
    __hip_bfloat16* Wcdb  = (__hip_bfloat16*)p; p += (size_t)NC * 1024 * 2;
    __hip_bfloat16* X1a = (__hip_bfloat16*)p; p += (size_t)BB * KA * 2;
    __hip_bfloat16* X1b = (__hip_bfloat16*)p; p += (size_t)BB * KA * 2;
    __hip_bfloat16* X2a = (__hip_bfloat16*)p; p += (size_t)BB * KA * 2;
    __hip_bfloat16* X2b = (__hip_bfloat16*)p; p += (size_t)BB * KA * 2;
    float* c1 = (float*)p; p += (size_t)SD * BB * 4;
    float* c2 = (float*)p; p += (size_t)SD * BB * 4;
    unsigned* bar = (unsigned*)p; p += 256;

    // ---- prep ----
    f2b_kernel<<<16384, 256, 0, stream>>>(h, hbf, BB * TT * SD);
    prep_small_kernel<<<256, 256, 0, stream>>>(Wphi, Wpsi, Wcd, Wphib, Wpsib, Wcdb);
    prep_w_kernel<<<18432, 256, 0, stream>>>(Wih0, Whh0, bih0, bhh0,
                                             Wih1, Whh1, bih1, bhh1, W1aug, W2aug);
    init_kernel<<<288, 256, 0, stream>>>(h, x, X1a, X1b, X2a, X2b, c1, c2, bar);
    psi_gemm_kernel<<<512, 256, 0, stream>>>(hbf, Wpsib, bpsi, psibf);

    // ---- persistent decode: PLAIN launch (cooperative launch failed in this
    // harness -> all-zero output in R3). grid=256 blocks x 4 waves x 16KB LDS:
    // per-CU capacity >= 2 blocks => all 256 blocks co-resident => spin barrier safe.
    decode_kernel<<<NBLK, 256, 0, stream>>>(
        W1aug, W2aug, Wphib, bphi, psibf, hbf, Wcdb, bcd,
        X1a, X1b, X2a, X2b, c1, c2, scbf, x, out, bar);
}

// Round 5
// 12669.016 us; speedup vs baseline: 1.9709x; 1.9709x over previous
//
#include <hip/hip_runtime.h>
#include <hip/hip_bf16.h>
#include <math.h>

#define BB 64      // batch
#define TT 512     // encoder time
#define NS 128     // decode steps
#define SD 512     // lstm hidden
#define ATT 128
#define NC 64      // num classes
#define KA 1152    // augmented K: 512 in + 512 rec + 64 onehot + 1 bias + 63 pad
#define NBLK 256   // persistent grid (capacity >= 2 blocks/CU at 256 VGPR -> all resident)

typedef __attribute__((ext_vector_type(8))) short bf8;   // 8 bf16 (4 VGPRs)
typedef __attribute__((ext_vector_type(4))) float f4;

__device__ __forceinline__ float sigm(float x) { return 1.0f / (1.0f + expf(-x)); }
__device__ __forceinline__ float b2f(short s) {
    union { unsigned u; float f; } c; c.u = ((unsigned)(unsigned short)s) << 16; return c.f;
}
#define MFMA16(a, b, c) __builtin_amdgcn_mfma_f32_16x16x32_bf16((a), (b), (c), 0, 0, 0)

// ---- coherent (agent-scope, cache-bypassing) access helpers ----
// These emit sc0/sc1 loads/stores that read/write the coherence point directly.
// NO fences -> no buffer_inv/buffer_wbl2 -> L2 stays warm for read-only data.
__device__ __forceinline__ unsigned long long cload64(const void* p) {
    return __hip_atomic_load((const unsigned long long*)p, __ATOMIC_RELAXED,
                             __HIP_MEMORY_SCOPE_AGENT);
}
__device__ __forceinline__ bf8 cload_bf8(const __hip_bfloat16* p) {
    union { bf8 v; unsigned long long u[2]; } r;
    const unsigned long long* q = (const unsigned long long*)p;
    r.u[0] = __hip_atomic_load(q,     __ATOMIC_RELAXED, __HIP_MEMORY_SCOPE_AGENT);
    r.u[1] = __hip_atomic_load(q + 1, __ATOMIC_RELAXED, __HIP_MEMORY_SCOPE_AGENT);
    return r.v;
}
__device__ __forceinline__ void cstore16(__hip_bfloat16* p, __hip_bfloat16 v) {
    __hip_atomic_store((unsigned short*)p, *(unsigned short*)&v,
                       __ATOMIC_RELAXED, __HIP_MEMORY_SCOPE_AGENT);
}

// ---- epoch grid barrier: fence-free ----
// __syncthreads() drains each wave's vmcnt (write-through stores globally visible
// at retire); consumers use cache-bypassing loads, so no invalidation is needed.
__device__ __forceinline__ void gbar(unsigned* bar, unsigned target) {
    __syncthreads();
    if (threadIdx.x == 0) {
        __hip_atomic_fetch_add(bar, 1u, __ATOMIC_RELAXED, __HIP_MEMORY_SCOPE_AGENT);
        while (__hip_atomic_load(bar, __ATOMIC_RELAXED, __HIP_MEMORY_SCOPE_AGENT) < target)
            __builtin_amdgcn_s_sleep(1);
    }
    __syncthreads();
}

// ---------------- fp32 -> bf16 convert (vec4) ----------------
__global__ void f2b_kernel(const float* __restrict__ src, __hip_bfloat16* __restrict__ dst, int n)
{
    int i = (blockIdx.x * blockDim.x + threadIdx.x) * 4;
    if (i < n) {
        float4 v = *(const float4*)(src + i);
        dst[i]     = __hip_bfloat16(v.x);
        dst[i + 1] = __hip_bfloat16(v.y);
        dst[i + 2] = __hip_bfloat16(v.z);
        dst[i + 3] = __hip_bfloat16(v.w);
    }
}

// ---------------- small weights bf16 convert ----------------
__global__ void prep_small_kernel(const float* __restrict__ Wphi, const float* __restrict__ Wpsi,
                                  const float* __restrict__ Wcd,
                                  __hip_bfloat16* __restrict__ Wphib, __hip_bfloat16* __restrict__ Wpsib,
                                  __hip_bfloat16* __restrict__ Wcdb)
{
    int i = blockIdx.x * 256 + threadIdx.x;
    Wphib[i] = __hip_bfloat16(Wphi[i]);
    Wpsib[i] = __hip_bfloat16(Wpsi[i]);
    Wcdb[i]  = __hip_bfloat16(Wcd[i]);
}

// ---------------- build augmented LSTM weights, gate-interleaved np=4d+q ----------------
__global__ void prep_w_kernel(const float* __restrict__ Wih0, const float* __restrict__ Whh0,
                              const float* __restrict__ bih0, const float* __restrict__ bhh0,
                              const float* __restrict__ Wih1, const float* __restrict__ Whh1,
                              const float* __restrict__ bih1, const float* __restrict__ bhh1,
                              __hip_bfloat16* __restrict__ W1, __hip_bfloat16* __restrict__ W2)
{
    int idx = blockIdx.x * 256 + threadIdx.x;
    const int half = 2048 * KA;
    if (idx >= 2 * half) return;
    int which = idx >= half;
    int id = idx - which * half;
    int np = id / KA, kk = id - np * KA;
    int q = np & 3, d = np >> 2, j = q * 512 + d;
    float v = 0.f;
    if (!which) {
        if (kk < 512)        v = Wih0[j * 576 + 64 + kk];
        else if (kk < 1024)  v = Whh0[j * 512 + kk - 512];
        else if (kk < 1088)  v = Wih0[j * 576 + kk - 1024];
        else if (kk == 1088) v = bih0[j] + bhh0[j];
        W1[id] = __hip_bfloat16(v);
    } else {
        if (kk < 512)        v = Wih1[j * 512 + kk];
        else if (kk < 1024)  v = Whh1[j * 512 + kk - 512];
        else if (kk == 1088) v = bih1[j] + bhh1[j];
        W2[id] = __hip_bfloat16(v);
    }
}

// ---------------- init: X buffers, c states, barrier counter ----------------
__global__ void init_kernel(const float* __restrict__ h, const int* __restrict__ x,
                            __hip_bfloat16* __restrict__ X1a, __hip_bfloat16* __restrict__ X1b,
                            __hip_bfloat16* __restrict__ X2a, __hip_bfloat16* __restrict__ X2b,
                            float* __restrict__ c1, float* __restrict__ c2,
                            unsigned* __restrict__ bar)
{
    int idx = blockIdx.x * blockDim.x + threadIdx.x;   // 64*1152
    if (blockIdx.x == 0 && threadIdx.x == 0) *bar = 0u;
    if (idx >= 64 * KA) return;
    int b = idx / KA, col = idx - b * KA;
    __hip_bfloat16 zero(0.0f), one(1.0f);
    __hip_bfloat16 v1a = zero, vo = zero;
    if (col < 512)        v1a = __hip_bfloat16(h[(size_t)b * TT * SD + col]);  // ctx0 = h[:,0,:]
    else if (col >= 1024 && col < 1088) v1a = (x[b * NS] == col - 1024) ? one : zero;
    if (col == 1088) { v1a = one; vo = one; }
    X1a[idx] = v1a; X1b[idx] = vo; X2a[idx] = vo; X2b[idx] = vo;
    if (idx < 512 * 64) { c1[idx] = 0.f; c2[idx] = 0.f; }
}

// ---------------- psi GEMM: psibf[b*512+t][128] = hbf @ Wpsi^T + bpsi ----------------
__global__ __launch_bounds__(256) void psi_gemm_kernel(
    const __hip_bfloat16* __restrict__ A,   // hbf [32768][512]
    const __hip_bfloat16* __restrict__ Bw,  // Wpsibf [128][512]
    const float* __restrict__ bias,
    __hip_bfloat16* __restrict__ C)         // [32768][128]
{
    int lane = threadIdx.x & 63, wave = threadIdx.x >> 6;
    int m0 = (blockIdx.x * 4 + wave) * 16;
    int mr = lane & 15, quad = lane >> 4;
    const bf8* Ar = (const bf8*)(A + (size_t)(m0 + mr) * 512 + quad * 8);
    f4 acc[8] = {};
    for (int k0 = 0; k0 < 512; k0 += 32) {
        int ko = k0 >> 3;
        bf8 a = Ar[ko];
#pragma unroll
        for (int nf = 0; nf < 8; ++nf) {
            const bf8* Br = (const bf8*)(Bw + (size_t)(nf * 16 + mr) * 512 + quad * 8);
            acc[nf] = MFMA16(a, Br[ko], acc[nf]);
        }
    }
#pragma unroll
    for (int nf = 0; nf < 8; ++nf) {
        int n = nf * 16 + mr;
        float bs = bias[n];
#pragma unroll
        for (int r = 0; r < 4; ++r) {
            int m = m0 + quad * 4 + r;
            C[(size_t)m * 128 + n] = __hip_bfloat16(acc[nf][r] + bs);
        }
    }
}

// ---------------- LSTM phase: K-split 4 waves, coherent X loads, LDS reduce, cell ----------------
__device__ __forceinline__ void lstm_phase(
    const __hip_bfloat16* __restrict__ X,    // [64][1152]  (coherent reads)
    const __hip_bfloat16* __restrict__ W,    // [2048][1152] gate-interleaved (cached reads)
    float* __restrict__ c,                   // block-private -> cached
    __hip_bfloat16* dst1, int rs1,
    __hip_bfloat16* dst2, int rs2,
    float* smem, int bid, int tid)
{
    int lane = tid & 63, w = tid >> 6;
    int mr = lane & 15, quad = lane >> 4;
    int m0 = bid * 16;
    int kbase = w * 288 + quad * 8;          // this wave's K-slice
    const bf8* Ar = (const bf8*)(W + (size_t)(m0 + mr) * KA + kbase);
    const __hip_bfloat16* b0p = X + (size_t)(mr)      * KA + kbase;
    const __hip_bfloat16* b1p = X + (size_t)(16 + mr) * KA + kbase;
    const __hip_bfloat16* b2p = X + (size_t)(32 + mr) * KA + kbase;
    const __hip_bfloat16* b3p = X + (size_t)(48 + mr) * KA + kbase;
    f4 a0 = {0,0,0,0}, a1 = {0,0,0,0}, a2 = {0,0,0,0}, a3 = {0,0,0,0};
#pragma unroll
    for (int i = 0; i < 9; ++i) {
        bf8 av = Ar[i * 4];
        bf8 b0 = cload_bf8(b0p + i * 32);
        bf8 b1 = cload_bf8(b1p + i * 32);
        bf8 b2 = cload_bf8(b2p + i * 32);
        bf8 b3 = cload_bf8(b3p + i * 32);
        a0 = MFMA16(av, b0, a0);
        a1 = MFMA16(av, b1, a1);
        a2 = MFMA16(av, b2, a2);
        a3 = MFMA16(av, b3, a3);
    }
    f4 accs[4] = {a0, a1, a2, a3};
#pragma unroll
    for (int nf = 0; nf < 4; ++nf)
#pragma unroll
        for (int r = 0; r < 4; ++r)
            smem[w * 1024 + (quad * 4 + r) * 64 + nf * 16 + mr] = accs[nf][r];
    __syncthreads();
    // epilogue: thread (d_loc, b)
    int d_loc = tid >> 6, b = tid & 63;
    float g[4];
#pragma unroll
    for (int q = 0; q < 4; ++q) {
        int m = d_loc * 4 + q;
        g[q] = smem[m * 64 + b] + smem[1024 + m * 64 + b]
             + smem[2048 + m * 64 + b] + smem[3072 + m * 64 + b];
    }
    int d = bid * 4 + d_loc;
    int ci = d * 64 + b;
    float cn = sigm(g[1]) * c[ci] + sigm(g[0]) * tanhf(g[2]);
    float hn = sigm(g[3]) * tanhf(cn);
    c[ci] = cn;
    __hip_bfloat16 hb(hn);
    cstore16(dst1 + (size_t)b * rs1 + d, hb);
    cstore16(dst2 + (size_t)b * rs2 + d, hb);
}

// ---------------- attention phase ----------------
__device__ __forceinline__ void attn_phase(
    const __hip_bfloat16* __restrict__ X2n,   // h2 at cols 512:1024 (coherent reads)
    const __hip_bfloat16* __restrict__ Wphib, const float* __restrict__ bphi,
    const __hip_bfloat16* __restrict__ psib,  // read-only -> cached
    const __hip_bfloat16* __restrict__ hbf,   // read-only -> cached
    __hip_bfloat16* X1n, __hip_bfloat16* scb,
    const int* __restrict__ xtok, int t,
    float* smem, int bid, int tid)
{
    int b = bid >> 2, dch = bid & 3;
    float* h2s  = smem;
    float* phis = smem + 512;
    float* es   = smem + 1024;
    float* red  = smem + 1536;

    if (tid < 128) {
        unsigned long long v = cload64((const unsigned long long*)
            ((const short*)X2n + (size_t)b * KA + 512) + tid);
#pragma unroll
        for (int j = 0; j < 4; ++j)
            h2s[tid * 4 + j] = b2f((short)(v >> (16 * j)));
    }
    __syncthreads();

    // phi[a] = h2 . Wphi[a] + bphi[a];  4 lanes/row
    {
        int al = tid & 3;
#pragma unroll
        for (int pass = 0; pass < 2; ++pass) {
            int a = pass * 64 + (tid >> 2);
            const bf8* wr = (const bf8*)(Wphib + (size_t)a * 512 + al * 8);
            float acc = 0.f;
#pragma unroll
            for (int i = 0; i < 16; ++i) {
                bf8 wv = wr[i * 4];
                const float* hp = h2s + i * 32 + al * 8;
#pragma unroll
                for (int j = 0; j < 8; ++j) acc += hp[j] * b2f(wv[j]);
            }
            acc += __shfl_xor(acc, 1);
            acc += __shfl_xor(acc, 2);
            if (al == 0) phis[a] = acc + bphi[a];
        }
    }
    __syncthreads();

    // e[t'] = phi . psi[b][t'];  4 lanes/row
    {
        int al = tid & 3;
#pragma unroll
        for (int pass = 0; pass < 8; ++pass) {
            int tt = pass * 64 + (tid >> 2);
            const bf8* pr = (const bf8*)(psib + (size_t)(b * TT + tt) * 128 + al * 8);
            float acc = 0.f;
#pragma unroll
            for (int i = 0; i < 4; ++i) {
                bf8 pv = pr[i * 4];
                const float* ph = phis + i * 32 + al * 8;
#pragma unroll
                for (int j = 0; j < 8; ++j) acc += ph[j] * b2f(pv[j]);
            }
            acc += __shfl_xor(acc, 1);
            acc += __shfl_xor(acc, 2);
            if (al == 0) es[tt] = acc;
        }
    }
    __syncthreads();

    // softmax (unnormalized; fold 1/sum into ctx)
    red[tid] = fmaxf(es[tid], es[tid + 256]);
    __syncthreads();
    for (int st = 128; st > 0; st >>= 1) {
        if (tid < st) red[tid] = fmaxf(red[tid], red[tid + st]);
        __syncthreads();
    }
    float mx = red[0];
    __syncthreads();
    float e0 = expf(es[tid] - mx), e1 = expf(es[tid + 256] - mx);
    es[tid] = e0; es[tid + 256] = e1;
    red[tid] = e0 + e1;
    __syncthreads();
    for (int st = 128; st > 0; st >>= 1) {
        if (tid < st) red[tid] += red[tid + st];
        __syncthreads();
    }
    float inv = 1.0f / red[0];
    __syncthreads();

    // ctx[d] = inv * sum_t es[t] * h[b][t][d], d-chunk of 128
    {
        int d = dch * 128 + (tid & 127), th = tid >> 7;
        const short* hp = (const short*)hbf + ((size_t)b * TT + th * 256) * SD + d;
        float s0 = 0.f, s1 = 0.f, s2 = 0.f, s3 = 0.f;
#pragma unroll 4
        for (int k = 0; k < 256; k += 4) {
            s0 += es[th * 256 + k]     * b2f(hp[(size_t)k * SD]);
            s1 += es[th * 256 + k + 1] * b2f(hp[(size_t)(k + 1) * SD]);
            s2 += es[th * 256 + k + 2] * b2f(hp[(size_t)(k + 2) * SD]);
            s3 += es[th * 256 + k + 3] * b2f(hp[(size_t)(k + 3) * SD]);
        }
        float acc = (s0 + s1) + (s2 + s3);
        red[tid] = acc;
        __syncthreads();
        if (th == 0) {
            float v = (acc + red[tid + 128]) * inv;
            __hip_bfloat16 vb(v);
            cstore16(X1n + (size_t)b * KA + d, vb);
            cstore16(scb + ((size_t)b * NS + t) * 1024 + 512 + d, vb);
        }
    }
    if (tid < 64) {
        float v = (t + 1 < NS && xtok[b * NS + t + 1] == tid) ? 1.0f : 0.0f;
        cstore16(X1n + (size_t)b * KA + 1024 + tid, __hip_bfloat16(v));
    }
}

// ---------------- persistent decode kernel (plain launch, grid=256) ----------------
__global__ __launch_bounds__(256, 1) void decode_kernel(
    const __hip_bfloat16* __restrict__ W1, const __hip_bfloat16* __restrict__ W2,
    const __hip_bfloat16* __restrict__ Wphib, const float* __restrict__ bphi,
    const __hip_bfloat16* __restrict__ psib, const __hip_bfloat16* __restrict__ hbf,
    const __hip_bfloat16* __restrict__ Wcdb, const float* __restrict__ bcd,
    __hip_bfloat16* X1a, __hip_bfloat16* X1b,
    __hip_bfloat16* X2a, __hip_bfloat16* X2b,
    float* c1, float* c2,
    __hip_bfloat16* scb, const int* __restrict__ xtok,
    float* out, unsigned* bar)
{
    __shared__ float smem[4096];
    int bid = blockIdx.x, tid = threadIdx.x;
    unsigned ep = 0;

    for (int t = 0; t < NS; ++t) {
        __hip_bfloat16 *X1c, *X1n, *X2c, *X2n;
        if (t & 1) { X1c = X1b; X1n = X1a; X2c = X2b; X2n = X2a; }
        else       { X1c = X1a; X1n = X1b; X2c = X2a; X2n = X2b; }

        if (bid < 128)
            lstm_phase(X1c, W1, c1, X2c, KA, X1n + 512, KA, smem, bid, tid);
        gbar(bar, ++ep * NBLK);

        if (bid < 128)
            lstm_phase(X2c, W2, c2, X2n + 512, KA, scb + (size_t)t * 1024, NS * 1024, smem, bid, tid);
        gbar(bar, ++ep * NBLK);

        attn_phase(X2n, Wphib, bphi, psib, hbf, X1n, scb, xtok, t, smem, bid, tid);
        gbar(bar, ++ep * NBLK);
    }

    // ---- output projection: out[m][n] = scb[m,:1024]·Wcd[n,:1024] + bcd[n] ----
    // scb was only ever written via write-through stores this dispatch -> no stale
    // L2 copies can exist -> normal cached vector loads are safe here.
    int lane = tid & 63, w = tid >> 6;
    int gw = bid * 4 + w;
    if (gw < 512) {
        int mr = lane & 15, quad = lane >> 4;
        int m0 = gw * 16;
        const bf8* Ar = (const bf8*)(scb + (size_t)(m0 + mr) * 1024 + quad * 8);
        f4 acc[4] = {};
        for (int k0 = 0; k0 < 1024; k0 += 32) {
            int ko = k0 >> 3;
            bf8 a = Ar[ko];
#pragma unroll
            for (int nf = 0; nf < 4; ++nf) {
                const bf8* Br = (const bf8*)(Wcdb + (size_t)(nf * 16 + mr) * 1024 + quad * 8);
                acc[nf] = MFMA16(a, Br[ko], acc[nf]);
            }
        }
#pragma unroll
        for (int nf = 0; nf < 4; ++nf) {
            int n = nf * 16 + mr;
            float bs = bcd[n];
#pragma unroll
            for (int r = 0; r < 4; ++r)
                out[(size_t)(m0 + quad * 4 + r) * 64 + n] = acc[nf][r] + bs;
        }
    }
}

extern "C" void kernel_launch(void* const* d_in, const int* in_sizes, int n_in,
                              void* d_out, int out_size, void* d_ws, size_t ws_size,
                              hipStream_t stream)
{
    const int*   x    = (const int*)  d_in[0];
    const float* h    = (const float*)d_in[1];
    const float* Wih0 = (const float*)d_in[2];
    const float* Whh0 = (const float*)d_in[3];
    const float* bih0 = (const float*)d_in[4];
    const float* bhh0 = (const float*)d_in[5];
    const float* Wih1 = (const float*)d_in[6];
    const float* Whh1 = (const float*)d_in[7];
    const float* bih1 = (const float*)d_in[8];
    const float* bhh1 = (const float*)d_in[9];
    const float* Wphi = (const float*)d_in[10];
    const float* bphi = (const float*)d_in[11];
    const float* Wpsi = (const float*)d_in[12];
    const float* bpsi = (const float*)d_in[13];
    const float* Wcd  = (const float*)d_in[14];
    const float* bcd  = (const float*)d_in[15];
    float* out = (float*)d_out;

    char* p = (char*)d_ws;
    __hip_bfloat16* hbf   = (__hip_bfloat16*)p; p += (size_t)BB * TT * SD * 2;   // 32 MB
    __hip_bfloat16* psibf = (__hip_bfloat16*)p; p += (size_t)BB * TT * ATT * 2;  // 8 MB
    __hip_bfloat16* scbf  = (__hip_bfloat16*)p; p += (size_t)BB * NS * 1024 * 2; // 16 MB
    __hip_bfloat16* W1aug = (__hip_bfloat16*)p; p += (size_t)2048 * KA * 2;      // 4.5 MB
    __hip_bfloat16* W2aug = (__hip_bfloat16*)p; p += (size_t)2048 * KA * 2;      // 4.5 MB
    __hip_bfloat16* Wphib = (__hip_bfloat16*)p; p += (size_t)ATT * SD * 2;
    __hip_bfloat16* Wpsib = (__hip_bfloat16*)p; p += (size_t)ATT * SD * 2;
    __hip_bfloat16* Wcdb  = (__hip_bfloat16*)p; p += (size_t)NC * 1024 * 2;
    __hip_bfloat16* X1a = (__hip_bfloat16*)p; p += (size_t)BB * KA * 2;
    __hip_bfloat16* X1b = (__hip_bfloat16*)p; p += (size_t)BB * KA * 2;
    __hip_bfloat16* X2a = (__hip_bfloat16*)p; p += (size_t)BB * KA * 2;
    __hip_bfloat16* X2b = (__hip_bfloat16*)p; p += (size_t)BB * KA * 2;
    float* c1 = (float*)p; p += (size_t)SD * BB * 4;
    float* c2 = (float*)p; p += (size_t)SD * BB * 4;
    unsigned* bar = (unsigned*)p; p += 256;

    // ---- prep ----
    f2b_kernel<<<16384, 256, 0, stream>>>(h, hbf, BB * TT * SD);
    prep_small_kernel<<<256, 256, 0, stream>>>(Wphi, Wpsi, Wcd, Wphib, Wpsib, Wcdb);
    prep_w_kernel<<<18432, 256, 0, stream>>>(Wih0, Whh0, bih0, bhh0,
                                             Wih1, Whh1, bih1, bhh1, W1aug, W2aug);
    init_kernel<<<288, 256, 0, stream>>>(h, x, X1a, X1b, X2a, X2b, c1, c2, bar);
    psi_gemm_kernel<<<512, 256, 0, stream>>>(hbf, Wpsib, bpsi, psibf);

    // ---- persistent decode (plain launch; all 256 blocks co-resident) ----
    decode_kernel<<<NBLK, 256, 0, stream>>>(
        W1aug, W2aug, Wphib, bphi, psibf, hbf, Wcdb, bcd,
        X1a, X1b, X2a, X2b, c1, c2, scbf, x, out, bar);
}

// Round 6
// 7781.579 us; speedup vs baseline: 3.2088x; 1.6281x over previous
//
#include <hip/hip_runtime.h>
#include <hip/hip_bf16.h>
#include <math.h>

#define BB 64      // batch
#define TT 512     // encoder time
#define NS 128     // decode steps
#define SD 512     // lstm hidden
#define ATT 128
#define NC 64      // num classes
#define KA 1152    // augmented K: 512 in + 512 rec + 64 onehot + 1 bias + 63 pad
#define NBLK 256

typedef __attribute__((ext_vector_type(8))) short bf8;   // 8 bf16
typedef __attribute__((ext_vector_type(4))) float f4;

__device__ __forceinline__ float sigm(float x) { return 1.0f / (1.0f + expf(-x)); }
__device__ __forceinline__ float b2f(short s) {
    union { unsigned u; float f; } c; c.u = ((unsigned)(unsigned short)s) << 16; return c.f;
}
#define MFMA16(a, b, c) __builtin_amdgcn_mfma_f32_16x16x32_bf16((a), (b), (c), 0, 0, 0)

// ---- write-through (agent-scope) stores; readers rely on fresh-address
// discipline (each address read only after its in-dispatch write, never
// cached earlier) so PLAIN cached loads are stale-free. ----
__device__ __forceinline__ void cstore16(__hip_bfloat16* p, __hip_bfloat16 v) {
    __hip_atomic_store((unsigned short*)p, *(unsigned short*)&v,
                       __ATOMIC_RELAXED, __HIP_MEMORY_SCOPE_AGENT);
}
__device__ __forceinline__ void cstore32f(float* p, float v) {
    union { float f; unsigned u; } c; c.f = v;
    __hip_atomic_store((unsigned*)p, c.u, __ATOMIC_RELAXED, __HIP_MEMORY_SCOPE_AGENT);
}
__device__ __forceinline__ unsigned long long cload64(const void* p) {
    return __hip_atomic_load((const unsigned long long*)p, __ATOMIC_RELAXED,
                             __HIP_MEMORY_SCOPE_AGENT);
}

// ---- epoch grid barrier with backoff (~0.2us polls) ----
__device__ __forceinline__ void gbar(unsigned* bar, unsigned target) {
    __syncthreads();
    if (threadIdx.x == 0) {
        __hip_atomic_fetch_add(bar, 1u, __ATOMIC_RELAXED, __HIP_MEMORY_SCOPE_AGENT);
        while (__hip_atomic_load(bar, __ATOMIC_RELAXED, __HIP_MEMORY_SCOPE_AGENT) < target)
            __builtin_amdgcn_s_sleep(8);
    }
    __syncthreads();
}

// ---------------- fp32 -> bf16 convert (vec4) ----------------
__global__ void f2b_kernel(const float* __restrict__ src, __hip_bfloat16* __restrict__ dst, int n)
{
    int i = (blockIdx.x * blockDim.x + threadIdx.x) * 4;
    if (i < n) {
        float4 v = *(const float4*)(src + i);
        dst[i]     = __hip_bfloat16(v.x);
        dst[i + 1] = __hip_bfloat16(v.y);
        dst[i + 2] = __hip_bfloat16(v.z);
        dst[i + 3] = __hip_bfloat16(v.w);
    }
}

// ---------------- transpose h[b][t][d] -> hT[b][d][t] (bf16) ----------------
__global__ __launch_bounds__(256) void transpose_kernel(const float* __restrict__ h,
                                                        __hip_bfloat16* __restrict__ hT)
{
    __shared__ float tile[64][65];
    int b = blockIdx.x, t0 = blockIdx.y * 64, d0 = blockIdx.z * 64;
#pragma unroll
    for (int k = 0; k < 16; ++k) {
        int lin = k * 256 + threadIdx.x;
        int tt = lin >> 6, dd = lin & 63;
        tile[tt][dd] = h[((size_t)b * TT + t0 + tt) * SD + d0 + dd];
    }
    __syncthreads();
#pragma unroll
    for (int k = 0; k < 16; ++k) {
        int lin = k * 256 + threadIdx.x;
        int dd = lin >> 6, tt = lin & 63;
        hT[((size_t)b * SD + d0 + dd) * TT + t0 + tt] = __hip_bfloat16(tile[tt][dd]);
    }
}

// ---------------- small weights bf16 convert ----------------
__global__ void prep_small_kernel(const float* __restrict__ Wphi, const float* __restrict__ Wpsi,
                                  const float* __restrict__ Wcd,
                                  __hip_bfloat16* __restrict__ Wphib, __hip_bfloat16* __restrict__ Wpsib,
                                  __hip_bfloat16* __restrict__ Wcdb)
{
    int i = blockIdx.x * 256 + threadIdx.x;
    Wphib[i] = __hip_bfloat16(Wphi[i]);
    Wpsib[i] = __hip_bfloat16(Wpsi[i]);
    Wcdb[i]  = __hip_bfloat16(Wcd[i]);
}

// ---------------- build augmented LSTM weights, gate-interleaved np=4d+q ----------------
__global__ void prep_w_kernel(const float* __restrict__ Wih0, const float* __restrict__ Whh0,
                              const float* __restrict__ bih0, const float* __restrict__ bhh0,
                              const float* __restrict__ Wih1, const float* __restrict__ Whh1,
                              const float* __restrict__ bih1, const float* __restrict__ bhh1,
                              __hip_bfloat16* __restrict__ W1, __hip_bfloat16* __restrict__ W2)
{
    int idx = blockIdx.x * 256 + threadIdx.x;
    const int half = 2048 * KA;
    if (idx >= 2 * half) return;
    int which = idx >= half;
    int id = idx - which * half;
    int np = id / KA, kk = id - np * KA;
    int q = np & 3, d = np >> 2, j = q * 512 + d;
    float v = 0.f;
    if (!which) {
        if (kk < 512)        v = Wih0[j * 576 + 64 + kk];
        else if (kk < 1024)  v = Whh0[j * 512 + kk - 512];
        else if (kk < 1088)  v = Wih0[j * 576 + kk - 1024];
        else if (kk == 1088) v = bih0[j] + bhh0[j];
        W1[id] = __hip_bfloat16(v);
    } else {
        if (kk < 512)        v = Wih1[j * 512 + kk];
        else if (kk < 1024)  v = Whh1[j * 512 + kk - 512];
        else if (kk == 1088) v = bih1[j] + bhh1[j];
        W2[id] = __hip_bfloat16(v);
    }
}

// ---------------- psiT GEMM: psiT[b][a][t'] = Wpsi[a,:]·h[b,t',:] + bpsi[a] ----------------
__global__ __launch_bounds__(256) void psiT_gemm_kernel(
    const __hip_bfloat16* __restrict__ hbf,   // [b*512+t][512]
    const __hip_bfloat16* __restrict__ Wpsib, // [128][512]
    const float* __restrict__ bpsi,
    __hip_bfloat16* __restrict__ psiT)        // [b][a][t']
{
    int lane = threadIdx.x & 63, w = threadIdx.x >> 6;
    int b = blockIdx.x >> 3, at = blockIdx.x & 7;
    int mr = lane & 15, quad = lane >> 4;
    int m0 = at * 16;
    const bf8* Ar = (const bf8*)(Wpsib + (size_t)(m0 + mr) * 512 + quad * 8);
    f4 acc[8] = {};
    for (int k0 = 0; k0 < 512; k0 += 32) {
        int ko = k0 >> 3;
        bf8 a = Ar[ko];
#pragma unroll
        for (int nf = 0; nf < 8; ++nf) {
            const bf8* Br = (const bf8*)(hbf + ((size_t)b * TT + w * 128 + nf * 16 + mr) * 512 + quad * 8);
            acc[nf] = MFMA16(a, Br[ko], acc[nf]);
        }
    }
#pragma unroll
    for (int nf = 0; nf < 8; ++nf) {
#pragma unroll
        for (int r = 0; r < 4; ++r) {
            int a = m0 + quad * 4 + r;
            int tp = w * 128 + nf * 16 + mr;
            psiT[((size_t)b * ATT + a) * TT + tp] = __hip_bfloat16(acc[nf][r] + bpsi[a]);
        }
    }
}

// ---------------- init: X const cols (incl. all onehots), step-0 state, c, bar ----------------
__global__ void init_kernel(const float* __restrict__ h, const int* __restrict__ x,
                            __hip_bfloat16* __restrict__ Xb1, __hip_bfloat16* __restrict__ Xb2,
                            float* __restrict__ c1, float* __restrict__ c2,
                            unsigned* __restrict__ bar)
{
    int idx = blockIdx.x * 256 + threadIdx.x;
    if (idx == 0) *bar = 0u;
    const int NA = 128 * 64 * 128;               // const cols, all t
    __hip_bfloat16 zero(0.0f), one(1.0f);
    if (idx < NA) {
        int t = idx >> 13, r = idx & 8191;
        int b = r >> 7, cc = r & 127;
        size_t base = ((size_t)t * BB + b) * KA + 1024 + cc;
        __hip_bfloat16 v1 = (cc < 64) ? ((x[b * NS + t] == cc) ? one : zero)
                                      : ((cc == 64) ? one : zero);
        Xb1[base] = v1;
        Xb2[base] = (cc == 64) ? one : zero;
        return;
    }
    int i2 = idx - NA;
    if (i2 < 32768) {            // X1[0] ctx0 cols 0:512
        int b = i2 >> 9, c = i2 & 511;
        Xb1[(size_t)b * KA + c] = __hip_bfloat16(h[(size_t)b * TT * SD + c]);
        return;
    }
    i2 -= 32768;
    if (i2 < 32768) {            // X1[0] h1 cols 512:1024 = 0
        int b = i2 >> 9, c = i2 & 511;
        Xb1[(size_t)b * KA + 512 + c] = zero;
        return;
    }
    i2 -= 32768;
    if (i2 < 32768) {            // X2[0] h2 cols 512:1024 = 0
        int b = i2 >> 9, c = i2 & 511;
        Xb2[(size_t)b * KA + 512 + c] = zero;
        return;
    }
    i2 -= 32768;
    if (i2 < 32768) { c1[i2] = 0.f; c2[i2] = 0.f; }
}

// ---------------- LSTM phase: wave = 16 rows x full K x 16-batch slice ----------------
__device__ __forceinline__ void lstm_phase(
    const __hip_bfloat16* __restrict__ X,    // [64][1152] fresh-address cached
    const __hip_bfloat16* __restrict__ W,    // [2048][1152] L2-resident
    float* __restrict__ c,
    __hip_bfloat16* dst1, int rs1,
    __hip_bfloat16* dst2, int rs2,
    int bid, int tid)
{
    int lane = tid & 63, w = tid >> 6;
    int mr = lane & 15, quad = lane >> 4;
    int m0 = bid * 16;
    const bf8* Ar = (const bf8*)(W + (size_t)(m0 + mr) * KA + quad * 8);
    const bf8* Br = (const bf8*)(X + (size_t)(w * 16 + mr) * KA + quad * 8);
    f4 acc = {0, 0, 0, 0};
#pragma unroll
    for (int i = 0; i < 36; ++i) {
        bf8 av = Ar[i * 4];
        bf8 bv = __builtin_nontemporal_load(Br + i * 4);
        acc = MFMA16(av, bv, acc);
    }
    // C layout: col=lane&15 -> b within slice; row=quad*4+reg -> np=4d+q
    int d = bid * 4 + quad, b = w * 16 + mr, ci = d * 64 + b;
    float cn = sigm(acc[1]) * c[ci] + sigm(acc[0]) * tanhf(acc[2]);
    float hn = sigm(acc[3]) * tanhf(cn);
    c[ci] = cn;
    __hip_bfloat16 hb(hn);
    cstore16(dst1 + (size_t)b * rs1 + d, hb);
    cstore16(dst2 + (size_t)b * rs2 + d, hb);
}

// ---------------- S phase: phi, e via psiT, softmax, write alpha (64 blocks) ----------------
__device__ __forceinline__ void score_phase(
    const __hip_bfloat16* __restrict__ scb,   // h2 = scb[(b*NS+t)*1024 + 0:512] (fresh cached)
    const __hip_bfloat16* __restrict__ Wphib, const float* __restrict__ bphi,
    const __hip_bfloat16* __restrict__ psiT,  // L2-resident
    float* __restrict__ alpha, int t,
    float* smem, int b, int tid)
{
    float* h2s  = smem;          // 512
    float* phis = smem + 512;    // 128
    float* ep_  = smem + 640;    // 4*512
    float* red  = smem + 2688;   // 256
    int lane = tid & 63, w = tid >> 6;

    if (tid < 64) {
        bf8 v = ((const bf8*)(scb + ((size_t)b * NS + t) * 1024))[tid];
#pragma unroll
        for (int j = 0; j < 8; ++j) h2s[tid * 8 + j] = b2f(v[j]);
    }
    __syncthreads();

    // phi[a] = h2 . Wphi[a] + bphi[a];  4 lanes per a-row
    {
        int al = tid & 3;
#pragma unroll
        for (int pass = 0; pass < 2; ++pass) {
            int a = pass * 64 + (tid >> 2);
            const bf8* wr = (const bf8*)(Wphib + (size_t)a * 512 + al * 8);
            float acc = 0.f;
#pragma unroll
            for (int i = 0; i < 16; ++i) {
                bf8 wv = wr[i * 4];
                const float* hp = h2s + i * 32 + al * 8;
#pragma unroll
                for (int j = 0; j < 8; ++j) acc += hp[j] * b2f(wv[j]);
            }
            acc += __shfl_xor(acc, 1);
            acc += __shfl_xor(acc, 2);
            if (al == 0) phis[a] = acc + bphi[a];
        }
    }
    __syncthreads();

    // e[t'] partials: wave w covers a in [w*32, w*32+32), lane covers t' = lane*8..+8
    {
        float eacc[8] = {};
        for (int a0 = 0; a0 < 32; ++a0) {
            int a = w * 32 + a0;
            float pa = phis[a];
            bf8 pv = *(const bf8*)(psiT + ((size_t)b * ATT + a) * TT + lane * 8);
#pragma unroll
            for (int j = 0; j < 8; ++j) eacc[j] += pa * b2f(pv[j]);
        }
#pragma unroll
        for (int j = 0; j < 8; ++j) ep_[w * 512 + lane * 8 + j] = eacc[j];
    }
    __syncthreads();

    float e0 = ep_[tid] + ep_[512 + tid] + ep_[1024 + tid] + ep_[1536 + tid];
    float e1 = ep_[256 + tid] + ep_[768 + tid] + ep_[1280 + tid] + ep_[1792 + tid];
    red[tid] = fmaxf(e0, e1);
    __syncthreads();
    for (int st = 128; st > 0; st >>= 1) {
        if (tid < st) red[tid] = fmaxf(red[tid], red[tid + st]);
        __syncthreads();
    }
    float mx = red[0];
    __syncthreads();
    float x0 = expf(e0 - mx), x1 = expf(e1 - mx);
    red[tid] = x0 + x1;
    __syncthreads();
    for (int st = 128; st > 0; st >>= 1) {
        if (tid < st) red[tid] += red[tid + st];
        __syncthreads();
    }
    float inv = 1.0f / red[0];
    cstore32f(alpha + (size_t)b * TT + tid,       x0 * inv);
    cstore32f(alpha + (size_t)b * TT + 256 + tid, x1 * inv);
}

// ---------------- C phase: ctx = alpha . hT (256 blocks) ----------------
__device__ __forceinline__ void ctx_phase(
    const float* __restrict__ alpha,          // coherent (reused address)
    const __hip_bfloat16* __restrict__ hT,    // nt-streamed
    __hip_bfloat16* X1n, __hip_bfloat16* scb, int t,
    float* smem, int bid, int tid)
{
    int b = bid >> 2, dch = bid & 3;
    float* as_ = smem;          // 512
    {
        unsigned long long v = cload64(alpha + (size_t)b * TT + tid * 2);
        union { unsigned u; float f; } lo, hi;
        lo.u = (unsigned)v; hi.u = (unsigned)(v >> 32);
        as_[tid * 2] = lo.f; as_[tid * 2 + 1] = hi.f;
    }
    __syncthreads();
    int d = dch * 128 + (tid >> 1), th = tid & 1;
    const bf8* hp = (const bf8*)(hT + ((size_t)b * SD + d) * TT + th * 256);
    const float* ap = as_ + th * 256;
    float a0 = 0.f, a1 = 0.f;
#pragma unroll
    for (int i = 0; i < 32; i += 2) {
        bf8 h0 = __builtin_nontemporal_load(hp + i);
        bf8 h1 = __builtin_nontemporal_load(hp + i + 1);
#pragma unroll
        for (int j = 0; j < 8; ++j) {
            a0 += ap[i * 8 + j] * b2f(h0[j]);
            a1 += ap[i * 8 + 8 + j] * b2f(h1[j]);
        }
    }
    float acc = a0 + a1;
    acc += __shfl_xor(acc, 1);
    if (th == 0) {
        __hip_bfloat16 vb(acc);
        cstore16(X1n + (size_t)b * KA + d, vb);
        cstore16(scb + ((size_t)b * NS + t) * 1024 + 512 + d, vb);
    }
}

// ---------------- persistent decode kernel ----------------
__global__ __launch_bounds__(256, 1) void decode_kernel(
    const __hip_bfloat16* __restrict__ W1, const __hip_bfloat16* __restrict__ W2,
    const __hip_bfloat16* __restrict__ Wphib, const float* __restrict__ bphi,
    const __hip_bfloat16* __restrict__ psiT, const __hip_bfloat16* __restrict__ hT,
    const __hip_bfloat16* __restrict__ Wcdb, const float* __restrict__ bcd,
    __hip_bfloat16* Xb1, __hip_bfloat16* Xb2,     // [129][64][1152] each
    float* c1, float* c2,
    __hip_bfloat16* scb, float* alpha,
    float* out, unsigned* bar)
{
    __shared__ float smem[4096];
    int bid = blockIdx.x, tid = threadIdx.x;
    unsigned ep = 0;

    for (int t = 0; t < NS; ++t) {
        __hip_bfloat16* X1 = Xb1 + (size_t)t * BB * KA;
        __hip_bfloat16* X2 = Xb2 + (size_t)t * BB * KA;
        __hip_bfloat16* X1n = Xb1 + (size_t)(t + 1) * BB * KA;
        __hip_bfloat16* X2n = Xb2 + (size_t)(t + 1) * BB * KA;

        if (bid < 128)   // L0: h1 -> X2[t][:,0:512] and X1[t+1][:,512:1024]
            lstm_phase(X1, W1, c1, X2, KA, X1n + 512, KA, bid, tid);
        gbar(bar, ++ep * NBLK);

        if (bid < 128)   // L1: h2 -> X2[t+1][:,512:1024] and scb[:,t,0:512]
            lstm_phase(X2, W2, c2, X2n + 512, KA, scb + (size_t)t * 1024, NS * 1024, bid, tid);
        gbar(bar, ++ep * NBLK);

        if (bid < 64)    // S: scores + softmax -> alpha
            score_phase(scb, Wphib, bphi, psiT, alpha, t, smem, bid, tid);
        gbar(bar, ++ep * NBLK);

        // C: ctx -> X1[t+1][:,0:512] and scb[:,t,512:1024]
        ctx_phase(alpha, hT, X1n, scb, t, smem, bid, tid);
        gbar(bar, ++ep * NBLK);
    }

    // ---- output projection: out = scb @ Wcd^T + bcd ----
    int lane = tid & 63, w = tid >> 6;
    int gw = bid * 4 + w;
    if (gw < 512) {
        int mr = lane & 15, quad = lane >> 4;
        int m0 = gw * 16;
        const bf8* Ar = (const bf8*)(scb + (size_t)(m0 + mr) * 1024 + quad * 8);
        f4 acc[4] = {};
        for (int k0 = 0; k0 < 1024; k0 += 32) {
            int ko = k0 >> 3;
            bf8 a = __builtin_nontemporal_load(Ar + ko);
#pragma unroll
            for (int nf = 0; nf < 4; ++nf) {
                const bf8* Br = (const bf8*)(Wcdb + (size_t)(nf * 16 + mr) * 1024 + quad * 8);
                acc[nf] = MFMA16(a, Br[ko], acc[nf]);
            }
        }
#pragma unroll
        for (int nf = 0; nf < 4; ++nf) {
            int n = nf * 16 + mr;
            float bs = bcd[n];
#pragma unroll
            for (int r = 0; r < 4; ++r)
                out[(size_t)(m0 + quad * 4 + r) * 64 + n] = acc[nf][r] + bs;
        }
    }
}

extern "C" void kernel_launch(void* const* d_in, const int* in_sizes, int n_in,
                              void* d_out, int out_size, void* d_ws, size_t ws_size,
                              hipStream_t stream)
{
    const int*   x    = (const int*)  d_in[0];
    const float* h    = (const float*)d_in[1];
    const float* Wih0 = (const float*)d_in[2];
    const float* Whh0 = (const float*)d_in[3];
    const float* bih0 = (const float*)d_in[4];
    const float* bhh0 = (const float*)d_in[5];
    const float* Wih1 = (const float*)d_in[6];
    const float* Whh1 = (const float*)d_in[7];
    const float* bih1 = (const float*)d_in[8];
    const float* bhh1 = (const float*)d_in[9];
    const float* Wphi = (const float*)d_in[10];
    const float* bphi = (const float*)d_in[11];
    const float* Wpsi = (const float*)d_in[12];
    const float* bpsi = (const float*)d_in[13];
    const float* Wcd  = (const float*)d_in[14];
    const float* bcd  = (const float*)d_in[15];
    float* out = (float*)d_out;

    char* p = (char*)d_ws;
    __hip_bfloat16* hT    = (__hip_bfloat16*)p; p += (size_t)BB * SD * TT * 2;     // 33.55 MB
    __hip_bfloat16* psiT  = (__hip_bfloat16*)p; p += (size_t)BB * ATT * TT * 2;    // 8.39 MB
    __hip_bfloat16* scbf  = (__hip_bfloat16*)p; p += (size_t)BB * NS * 1024 * 2;   // 16.78 MB
    __hip_bfloat16* W1aug = (__hip_bfloat16*)p; p += (size_t)2048 * KA * 2;        // 4.72 MB
    __hip_bfloat16* W2aug = (__hip_bfloat16*)p; p += (size_t)2048 * KA * 2;        // 4.72 MB
    __hip_bfloat16* Wphib = (__hip_bfloat16*)p; p += (size_t)ATT * SD * 2;
    __hip_bfloat16* Wpsib = (__hip_bfloat16*)p; p += (size_t)ATT * SD * 2;
    __hip_bfloat16* Wcdb  = (__hip_bfloat16*)p; p += (size_t)NC * 1024 * 2;
    float* alpha = (float*)p; p += (size_t)BB * TT * 4;                            // 131 KB
    float* c1    = (float*)p; p += (size_t)SD * BB * 4;
    float* c2    = (float*)p; p += (size_t)SD * BB * 4;
    unsigned* bar = (unsigned*)p; p += 256;
    __hip_bfloat16* Xb1 = (__hip_bfloat16*)p; p += (size_t)129 * BB * KA * 2;      // 19.02 MB
    __hip_bfloat16* Xb2 = (__hip_bfloat16*)p; p += (size_t)129 * BB * KA * 2;      // 19.02 MB
    // hbf (33.55 MB) aliases the Xb1+Xb2 region (38.04 MB): used only in prep,
    // before init_kernel overwrites X const cols (stream-ordered).
    __hip_bfloat16* hbf = Xb1;

    // ---- prep ----
    f2b_kernel<<<16384, 256, 0, stream>>>(h, hbf, BB * TT * SD);
    transpose_kernel<<<dim3(64, 8, 8), 256, 0, stream>>>(h, hT);
    prep_small_kernel<<<256, 256, 0, stream>>>(Wphi, Wpsi, Wcd, Wphib, Wpsib, Wcdb);
    prep_w_kernel<<<18432, 256, 0, stream>>>(Wih0, Whh0, bih0, bhh0,
                                             Wih1, Whh1, bih1, bhh1, W1aug, W2aug);
    psiT_gemm_kernel<<<512, 256, 0, stream>>>(hbf, Wpsib, bpsi, psiT);
    init_kernel<<<4608, 256, 0, stream>>>(h, x, Xb1, Xb2, c1, c2, bar);

    // ---- persistent decode (plain launch; 256 blocks, 2 blocks/CU capacity) ----
    decode_kernel<<<NBLK, 256, 0, stream>>>(
        W1aug, W2aug, Wphib, bphi, psiT, hT, Wcdb, bcd,
        Xb1, Xb2, c1, c2, scbf, alpha, out, bar);
}